// Round 9
// baseline (2879.776 us; speedup 1.0000x reference)
//
#include <hip/hip_runtime.h>
#include <hip/hip_fp16.h>
#include <stdint.h>

#define SEQ   1024
#define BATCH 128
#define INDIM 256
#define HID   512
#define INV_TAU 0.1f

typedef _Float16 f16;
typedef _Float16 f16x2 __attribute__((ext_vector_type(2)));
typedef _Float16 f16x8 __attribute__((ext_vector_type(8)));
typedef float    f32x4 __attribute__((ext_vector_type(4)));

static __device__ __forceinline__ f16x2 pk2(float a, float b) {
  auto r = __builtin_amdgcn_cvt_pkrtz(a, b);
  union { decltype(r) i; f16x2 o; } u;
  u.i = r;
  return u.o;
}

static __device__ __forceinline__ uint32_t f2u(f16x2 x) {
  union { f16x2 h; uint32_t u; } c; c.h = x; return c.u;
}

// ---------------------------------------------------------------------------
// K1: A = x @ win + bias  -> written into d_out (in place; K2 overwrites with h)
// ---------------------------------------------------------------------------
__global__ __launch_bounds__(512, 2)
void k1_gemm(const float* __restrict__ x, const float* __restrict__ win,
             const float* __restrict__ bias, float* __restrict__ out) {
  __shared__ __align__(16) f16x2 b_lds[HID][20];

  const int tid  = threadIdx.x;
  const int lane = tid & 63;
  const int wid  = tid >> 6;
  const int wr2  = wid >> 2;
  const int wc   = wid & 3;
  const int l15  = lane & 15;
  const int kg   = lane >> 4;

  const long m0 = (long)blockIdx.x * 64;

  f32x4 acc[2][8];
  #pragma unroll
  for (int a = 0; a < 2; ++a)
    #pragma unroll
    for (int bq = 0; bq < 8; ++bq) acc[a][bq] = (f32x4){0.f, 0.f, 0.f, 0.f};

  const int sp0 = (tid >> 8) * 8;
  const int sn0 = tid & 255;

  for (int ks = 0; ks < 8; ++ks) {
    const int k0 = ks * 32;
    #pragma unroll
    for (int r = 0; r < 8; ++r) {
      const int p = sp0 + r;
      #pragma unroll
      for (int i = 0; i < 2; ++i) {
        const int n = sn0 + 256 * i;
        const float lo = win[(k0 + 2 * p) * HID + n];
        const float hi = win[(k0 + 2 * p + 1) * HID + n];
        const int g  = p >> 2;
        const int gs = g ^ (n & 3);
        b_lds[n][gs * 4 + (p & 3)] = pk2(lo, hi);
      }
    }
    __syncthreads();

    f16x8 af[2];
    #pragma unroll
    for (int mf = 0; mf < 2; ++mf) {
      const long row = m0 + wr2 * 32 + mf * 16 + l15;
      const float4* xp = (const float4*)(x + row * INDIM + k0 + kg * 8);
      const float4 a0 = xp[0];
      const float4 a1 = xp[1];
      union { f16x2 h2[4]; f16x8 h8; } u;
      u.h2[0] = pk2(a0.x, a0.y); u.h2[1] = pk2(a0.z, a0.w);
      u.h2[2] = pk2(a1.x, a1.y); u.h2[3] = pk2(a1.z, a1.w);
      af[mf] = u.h8;
    }

    #pragma unroll
    for (int nf = 0; nf < 8; ++nf) {
      const int n  = wc * 128 + nf * 16 + l15;
      const int gs = kg ^ (n & 3);
      union { uint4 v; f16x8 h8; } u;
      u.v = *(const uint4*)&b_lds[n][gs * 4];
      #pragma unroll
      for (int mf = 0; mf < 2; ++mf)
        acc[mf][nf] = __builtin_amdgcn_mfma_f32_16x16x32_f16(af[mf], u.h8, acc[mf][nf], 0, 0, 0);
    }
    __syncthreads();
  }

  #pragma unroll
  for (int nf = 0; nf < 8; ++nf) {
    const int col = wc * 128 + nf * 16 + l15;
    const float bc = bias[col];
    #pragma unroll
    for (int mf = 0; mf < 2; ++mf) {
      const long rowb = m0 + wr2 * 32 + mf * 16 + kg * 4;
      #pragma unroll
      for (int r = 0; r < 4; ++r)
        out[(rowb + r) * HID + col] = acc[mf][nf][r] + bc;
    }
  }
}

// ---------------------------------------------------------------------------
// K2: per-batch-row recurrence, 128 blocks x 512 threads, 1 block/CU.
//
// MODEL (rounds 0-8):
//  - compiler scratch-spills any large loop-invariant VGPR mass (r0-r4)
//  - cross-CU exchange = 2-3us/step latency (r1/r6): dead
//  - AGPR pinning works (r7: WRITE_SIZE exactly 262144KB, 0 conflicts) BUT
//    r7 ran at 1 wave/SIMD (Occupancy 12% = AGPR 184 + VGPR 128 = 312 > 256)
//    with serial read->fma pairs -> 6300cy/step of bubbles nothing could hide
//  - v_pk_fma_f16 CANNOT source AGPRs directly (r8 assembler reject):
//    the v_accvgpr_read is unavoidable.
//
// THIS ROUND: keep r7's proven mapping; fix the two measured stalls.
//  1) Batched asm blocks: per k-pair, 8 independent v_accvgpr_read into 8
//     temps THEN 8 v_pk_fma_f16 -- read latency amortized 8-wide.  Blocks
//     are non-volatile but input the loop-variant h value, so they can't be
//     hoisted out of the loop (the r0-r4 spill mechanism); the scheduler
//     can interleave neighboring blocks (independent acc chains).
//  2) VGPR diet for 2 waves/SIMD: AGPR 184 + VGPR<=72 fits 256.  hu[8]
//     array (32 regs) -> 2-deep rolling prefetch (8 regs); 8 rotating
//     read-temps; amdgpu_waves_per_eu(2) hint (demand now actually fits).
//
// Layout per thread (q = tid&7: k in [64q,64q+64); cols 8jj..8jj+7;
// owner col = tid): 23 k-pairs x 8 cols in AGPR, 9 k-pairs in 144KB LDS
// (self-owned lane-consecutive planes, 0 conflicts), h broadcast uint4
// XOR-swizzled, halving-butterfly octet reduce, coalesced out, 1 barrier.
// ---------------------------------------------------------------------------
#define K2_SMEM (147456 + 2048)

#define DECL_A(n) uint32_t A##n##_0, A##n##_1, A##n##_2, A##n##_3, \
                           A##n##_4, A##n##_5, A##n##_6, A##n##_7;

#define WRA(d, s) asm volatile("v_accvgpr_write_b32 %0, %1" : "=a"(d) : "v"(s));

#define INIT_A(n) { \
  const float* r0_ = wq + (long)(2 * (n)) * HID; \
  const float* r1_ = r0_ + HID; \
  const float2 xa_ = *(const float2*)(r0_    ), ya_ = *(const float2*)(r1_    ); \
  const float2 xb_ = *(const float2*)(r0_ + 2), yb_ = *(const float2*)(r1_ + 2); \
  const float2 xc_ = *(const float2*)(r0_ + 4), yc_ = *(const float2*)(r1_ + 4); \
  const float2 xd_ = *(const float2*)(r0_ + 6), yd_ = *(const float2*)(r1_ + 6); \
  WRA(A##n##_0, f2u(pk2(xa_.x, ya_.x)))  WRA(A##n##_1, f2u(pk2(xa_.y, ya_.y))) \
  WRA(A##n##_2, f2u(pk2(xb_.x, yb_.x)))  WRA(A##n##_3, f2u(pk2(xb_.y, yb_.y))) \
  WRA(A##n##_4, f2u(pk2(xc_.x, yc_.x)))  WRA(A##n##_5, f2u(pk2(xc_.y, yc_.y))) \
  WRA(A##n##_6, f2u(pk2(xd_.x, yd_.x)))  WRA(A##n##_7, f2u(pk2(xd_.y, yd_.y))) }

// One k-pair: 8 pipelined accvgpr_reads, then 8 pk_fma.  Non-volatile;
// depends on HH (loop-variant) so it is not loop-invariant-hoistable.
#define FMA_A(n, HH) { \
  const f16x2 hh_ = (HH); \
  uint32_t t0_, t1_, t2_, t3_, t4_, t5_, t6_, t7_; \
  asm("v_accvgpr_read_b32 %8, %17\n\t"  \
      "v_accvgpr_read_b32 %9, %18\n\t"  \
      "v_accvgpr_read_b32 %10, %19\n\t" \
      "v_accvgpr_read_b32 %11, %20\n\t" \
      "v_accvgpr_read_b32 %12, %21\n\t" \
      "v_accvgpr_read_b32 %13, %22\n\t" \
      "v_accvgpr_read_b32 %14, %23\n\t" \
      "v_accvgpr_read_b32 %15, %24\n\t" \
      "v_pk_fma_f16 %0, %16, %8, %0\n\t"  \
      "v_pk_fma_f16 %1, %16, %9, %1\n\t"  \
      "v_pk_fma_f16 %2, %16, %10, %2\n\t" \
      "v_pk_fma_f16 %3, %16, %11, %3\n\t" \
      "v_pk_fma_f16 %4, %16, %12, %4\n\t" \
      "v_pk_fma_f16 %5, %16, %13, %5\n\t" \
      "v_pk_fma_f16 %6, %16, %14, %6\n\t" \
      "v_pk_fma_f16 %7, %16, %15, %7"     \
      : "+v"(a0), "+v"(a1), "+v"(a2), "+v"(a3), \
        "+v"(a4), "+v"(a5), "+v"(a6), "+v"(a7), \
        "=&v"(t0_), "=&v"(t1_), "=&v"(t2_), "=&v"(t3_), \
        "=&v"(t4_), "=&v"(t5_), "=&v"(t6_), "=&v"(t7_)  \
      : "v"(hh_), \
        "a"(A##n##_0), "a"(A##n##_1), "a"(A##n##_2), "a"(A##n##_3), \
        "a"(A##n##_4), "a"(A##n##_5), "a"(A##n##_6), "a"(A##n##_7)); }

// One LDS-resident k-pair: 2 self-owned lane-consecutive b128 reads + 8 fma
#define FMA_L(n, HH) { \
  const f16x2 hh_ = (HH); \
  union { uint4 v; f16x2 h2[4]; } w0_, w1_; \
  w0_.v = w4t[(2 * ((n) - 23)    ) * 512]; \
  w1_.v = w4t[(2 * ((n) - 23) + 1) * 512]; \
  a0 = __builtin_elementwise_fma(hh_, w0_.h2[0], a0); \
  a1 = __builtin_elementwise_fma(hh_, w0_.h2[1], a1); \
  a2 = __builtin_elementwise_fma(hh_, w0_.h2[2], a2); \
  a3 = __builtin_elementwise_fma(hh_, w0_.h2[3], a3); \
  a4 = __builtin_elementwise_fma(hh_, w1_.h2[0], a4); \
  a5 = __builtin_elementwise_fma(hh_, w1_.h2[1], a5); \
  a6 = __builtin_elementwise_fma(hh_, w1_.h2[2], a6); \
  a7 = __builtin_elementwise_fma(hh_, w1_.h2[3], a7); }

__global__ __launch_bounds__(512)
__attribute__((amdgpu_waves_per_eu(2)))
void k2_rnn(const float* __restrict__ wr, float* __restrict__ out) {
  extern __shared__ char smem[];
  uint4*    w4  = (uint4*)smem;                    // 18 planes x 512 x 16B = 144KB
  uint32_t* hbs = (uint32_t*)(smem + 147456);      // [2][256] u32 = 2KB (h, f16)

  const int tid = threadIdx.x;
  const int q   = tid & 7;        // k-slice: k in [64q, 64q+64)  (kp 32q..32q+31)
  const int jj  = tid >> 3;       // cols 8jj .. 8jj+7
  const int b   = blockIdx.x;

  const float* wq = wr + (long)(64 * q) * HID + 8 * jj;

  DECL_A(0)  DECL_A(1)  DECL_A(2)  DECL_A(3)  DECL_A(4)  DECL_A(5)
  DECL_A(6)  DECL_A(7)  DECL_A(8)  DECL_A(9)  DECL_A(10) DECL_A(11)
  DECL_A(12) DECL_A(13) DECL_A(14) DECL_A(15) DECL_A(16) DECL_A(17)
  DECL_A(18) DECL_A(19) DECL_A(20) DECL_A(21) DECL_A(22)

  INIT_A(0)  INIT_A(1)  INIT_A(2)  INIT_A(3)  INIT_A(4)  INIT_A(5)
  INIT_A(6)  INIT_A(7)  INIT_A(8)  INIT_A(9)  INIT_A(10) INIT_A(11)
  INIT_A(12) INIT_A(13) INIT_A(14) INIT_A(15) INIT_A(16) INIT_A(17)
  INIT_A(18) INIT_A(19) INIT_A(20) INIT_A(21) INIT_A(22)

  // ---- LDS weight planes: k-pairs n in [23,32), plane pair 2(n-23)+cc
  #pragma unroll
  for (int n = 23; n < 32; ++n) {
    const float* r0 = wq + (long)(2 * n) * HID;
    const float* r1 = r0 + HID;
    #pragma unroll
    for (int cc = 0; cc < 2; ++cc) {
      union { uint4 v; f16x2 h2[4]; } u;
      #pragma unroll
      for (int m = 0; m < 4; ++m)
        u.h2[m] = pk2(r0[4 * cc + m], r1[4 * cc + m]);
      w4[(2 * (n - 23) + cc) * 512 + tid] = u.v;
    }
  }

  hbs[tid] = 0u;          // zero both h buffers (512 u32)
  __syncthreads();

  // swizzled write slot for h[col=tid]: logical uint4 W=tid>>3,
  // phys = (W&56) | ((W&7)^(W>>3)); f16 slot = phys*8 + (tid&7)
  const int Wn    = tid >> 3;
  const int physW = (Wn & 56) | ((Wn & 7) ^ (Wn >> 3));
  const int hpos  = physW * 8 + (tid & 7);

  const uint4* w4t = w4 + tid;

  float h  = 0.0f;
  float av = out[(long)b * HID + tid];   // A[0] prefetch (col = tid, coalesced)

  const f16x2 Z2 = {(f16)0.f, (f16)0.f};

  #pragma unroll 1
  for (int t = 0; t < SEQ; ++t) {
    const int cur = t & 1;
    const int nxt = cur ^ 1;
    const long aofs = ((long)t * BATCH + b) * HID;
    const int  tn   = (t + 1 < SEQ) ? (t + 1) : (SEQ - 1);
    const float av_next = out[((long)tn * BATCH + b) * HID + tid];

    const uint4* hb4 = ((const uint4*)hbs) + cur * 64;

    // rolling 2-deep prefetch of the XOR-swizzled h broadcast uint4s:
    // logical W = 8q+w lives at phys 8q+(w^q) -> 8 distinct bank groups
    union HU { uint4 v; f16x2 h2[4]; } ha, hbu;
    ha.v  = hb4[8 * q + (0 ^ q)];
    hbu.v = hb4[8 * q + (1 ^ q)];

    f16x2 a0 = Z2, a1 = Z2, a2 = Z2, a3 = Z2,
          a4 = Z2, a5 = Z2, a6 = Z2, a7 = Z2;

    // group 0 (kp 0-3) from ha, prefetch group 2
    FMA_A(0,  ha.h2[0]) FMA_A(1,  ha.h2[1]) FMA_A(2,  ha.h2[2]) FMA_A(3,  ha.h2[3])
    ha.v = hb4[8 * q + (2 ^ q)];
    // group 1 (kp 4-7) from hbu, prefetch group 3
    FMA_A(4,  hbu.h2[0]) FMA_A(5,  hbu.h2[1]) FMA_A(6,  hbu.h2[2]) FMA_A(7,  hbu.h2[3])
    hbu.v = hb4[8 * q + (3 ^ q)];
    // group 2 (kp 8-11)
    FMA_A(8,  ha.h2[0]) FMA_A(9,  ha.h2[1]) FMA_A(10, ha.h2[2]) FMA_A(11, ha.h2[3])
    ha.v = hb4[8 * q + (4 ^ q)];
    // group 3 (kp 12-15)
    FMA_A(12, hbu.h2[0]) FMA_A(13, hbu.h2[1]) FMA_A(14, hbu.h2[2]) FMA_A(15, hbu.h2[3])
    hbu.v = hb4[8 * q + (5 ^ q)];
    // group 4 (kp 16-19)
    FMA_A(16, ha.h2[0]) FMA_A(17, ha.h2[1]) FMA_A(18, ha.h2[2]) FMA_A(19, ha.h2[3])
    ha.v = hb4[8 * q + (6 ^ q)];
    // group 5 (kp 20-22 AGPR, kp 23 LDS)
    FMA_A(20, hbu.h2[0]) FMA_A(21, hbu.h2[1]) FMA_A(22, hbu.h2[2]) FMA_L(23, hbu.h2[3])
    hbu.v = hb4[8 * q + (7 ^ q)];
    // group 6 (kp 24-27 LDS)
    FMA_L(24, ha.h2[0]) FMA_L(25, ha.h2[1]) FMA_L(26, ha.h2[2]) FMA_L(27, ha.h2[3])
    // group 7 (kp 28-31 LDS)
    FMA_L(28, hbu.h2[0]) FMA_L(29, hbu.h2[1]) FMA_L(30, hbu.h2[2]) FMA_L(31, hbu.h2[3])

    // halving-butterfly reduce across the q-octet (lane bits 0..2)
    float y0 = (float)a0[0] + (float)a0[1];
    float y1 = (float)a1[0] + (float)a1[1];
    float y2 = (float)a2[0] + (float)a2[1];
    float y3 = (float)a3[0] + (float)a3[1];
    float y4 = (float)a4[0] + (float)a4[1];
    float y5 = (float)a5[0] + (float)a5[1];
    float y6 = (float)a6[0] + (float)a6[1];
    float y7 = (float)a7[0] + (float)a7[1];

    const float z0 = ((q & 4) ? y4 : y0) + __shfl_xor((q & 4) ? y0 : y4, 4);
    const float z1 = ((q & 4) ? y5 : y1) + __shfl_xor((q & 4) ? y1 : y5, 4);
    const float z2 = ((q & 4) ? y6 : y2) + __shfl_xor((q & 4) ? y2 : y6, 4);
    const float z3 = ((q & 4) ? y7 : y3) + __shfl_xor((q & 4) ? y3 : y7, 4);
    const float u0 = ((q & 2) ? z2 : z0) + __shfl_xor((q & 2) ? z0 : z2, 2);
    const float u1 = ((q & 2) ? z3 : z1) + __shfl_xor((q & 2) ? z1 : z3, 2);
    const float y  = ((q & 1) ? u1 : u0) + __shfl_xor((q & 1) ? u0 : u1, 1);
    // y = dot(h, wr[:, col]) for col = 8jj + q = tid

    // leaky update: h += 0.1*(tanh(A + y) - h)
    const float arg = av + y;
    const float e  = __expf(2.0f * arg);
    const float th = 1.0f - 2.0f / (e + 1.0f);
    h += INV_TAU * (th - h);

    out[aofs + tid] = h;                          // coalesced
    ((f16*)(hbs + nxt * 256))[hpos] = (f16)h;     // swizzled, conflict-free
    av = av_next;
    __syncthreads();
  }
}

// ---------------------------------------------------------------------------
extern "C" void kernel_launch(void* const* d_in, const int* in_sizes, int n_in,
                              void* d_out, int out_size, void* d_ws, size_t ws_size,
                              hipStream_t stream) {
  const float* x    = (const float*)d_in[0];
  const float* win  = (const float*)d_in[1];
  const float* wr   = (const float*)d_in[2];
  const float* bias = (const float*)d_in[3];
  float* out = (float*)d_out;

  (void)d_ws; (void)ws_size; (void)in_sizes; (void)n_in; (void)out_size;

  (void)hipFuncSetAttribute((const void*)k2_rnn,
                            hipFuncAttributeMaxDynamicSharedMemorySize, K2_SMEM);

  k1_gemm<<<dim3((SEQ * BATCH) / 64), dim3(512), 0, stream>>>(x, win, bias, out);
  k2_rnn<<<dim3(BATCH), dim3(512), K2_SMEM, stream>>>(wr, out);
}